// Round 1
// 1549.951 us; speedup vs baseline: 1.4198x; 1.4198x over previous
//
#include <hip/hip_runtime.h>
#include <hip/hip_bf16.h>

// IGCN round 4:
//  - SpMM kernels restructured: 4 neighbor sub-groups of 16 lanes (4 dims/lane,
//    8B vector loads) -> serial chain per row /4, per-edge instr ~/2.
//  - Propagated rep stored pre-scaled (t = dinv*rep): adjacency layer becomes a
//    plain masked sum (no dinv[c] gather, no per-edge weight shuffle), then
//    rep = dinv[r]*s, t_next = dinv[r]*rep. Algebraically identical to
//    rep' = D A D rep.
//  - Final GEMM: 128x128 tile, K=64 fully resident, transposed LDS tiles read
//    as float4 (ds_read_b128), 8x8 outputs/thread -> FMA-issue-bound.
//
// Memory: d_ws = [flag | acc fp32 64MB].
//         d_out scratch: src bf16 32MB | dst bf16 32MB | colA 16MB | cnt/
//         rowptr/cursor/dinv/dfinv 1MB each | total. GEMM overwrites d_out last.

namespace {
constexpr int kUsers = 100000;
constexpr int kItems = 150000;
constexpr int kN     = 250000;
constexpr int kEmb   = 64;
}

__device__ __forceinline__ float bfu2f(unsigned short u) {
  return __uint_as_float((unsigned)u << 16);
}
__device__ __forceinline__ unsigned short f2bfu(float f) {
  unsigned u = __float_as_uint(f);
  u += 0x7FFFu + ((u >> 16) & 1u);   // round-to-nearest-even
  return (unsigned short)(u >> 16);
}

// ---- dtype detector: flag=1 if fp32 storage, 0 if bf16 ----
__global__ void igcn_detect_f32(const unsigned short* __restrict__ u,
                                int* __restrict__ flag) {
  __shared__ int cnt;
  if (threadIdx.x == 0) cnt = 0;
  __syncthreads();
  int h = 0;
  for (int i = threadIdx.x; i < 4096; i += 256) {
    unsigned e = (u[i] >> 7) & 0xFFu;
    h += (e >= 0x8Eu) ? 1 : 0;
  }
  atomicAdd(&cnt, h);
  __syncthreads();
  if (threadIdx.x == 0) *flag = (cnt > 64) ? 1 : 0;
}

// ---- degree histogram ----
__global__ void igcn_hist(const int* __restrict__ row, int* __restrict__ cnt,
                          int nE) {
  int e = blockIdx.x * blockDim.x + threadIdx.x;
  if (e < nE) atomicAdd(&cnt[row[e]], 1);
}

// ---- segment assignment (scan-free CSR) ----
__global__ void igcn_assign(const int* __restrict__ cnt, int* __restrict__ rowptr,
                            int* __restrict__ cursor, float* __restrict__ dinv,
                            float* __restrict__ dfinv, int* __restrict__ total,
                            int n) {
  __shared__ int sdata[256];
  __shared__ int sbase;
  int r = blockIdx.x * 256 + threadIdx.x;
  int c = (r < n) ? cnt[r] : 0;
  sdata[threadIdx.x] = c;
  __syncthreads();
  for (int off = 1; off < 256; off <<= 1) {
    int v = sdata[threadIdx.x];
    int add = (threadIdx.x >= off) ? sdata[threadIdx.x - off] : 0;
    __syncthreads();
    sdata[threadIdx.x] = v + add;
    __syncthreads();
  }
  if (threadIdx.x == 255) sbase = atomicAdd(total, sdata[255]);
  __syncthreads();
  if (r < n) {
    int start = sbase + sdata[threadIdx.x] - c;
    rowptr[r] = start;
    cursor[r] = start;
    dinv[r]  = rsqrtf((float)(c > 0 ? c : 1));
    dfinv[r] = rsqrtf((float)(c + 1));
  }
}

// ---- scatter columns into CSR ----
__global__ void igcn_scatter(const int* __restrict__ row, const int* __restrict__ col,
                             int* __restrict__ cursor, int* __restrict__ colA,
                             int nE) {
  int e = blockIdx.x * blockDim.x + threadIdx.x;
  if (e >= nE) return;
  int p = atomicAdd(&cursor[row[e]], 1);
  colA[p] = col[e];
}

// ---- feature SpMM: rep = dfinv[r]*(sum emb[c] + emb[bias])*w ----
// acc := rep ; src := bf16(dinv[r]*rep)   (pre-scaled t for the adj layers)
// Wave layout: 4 groups of 16 lanes; group g handles neighbor j+g; each lane
// owns dims q*4..q*4+3 (8B/16B vector loads). Tail masked by vf in {0,1}.
__global__ void igcn_feat_spmm(const int* __restrict__ rowptr,
                               const int* __restrict__ cnt,
                               const int* __restrict__ colA,
                               const float* __restrict__ dfinv,
                               const float* __restrict__ dinv,
                               const void* __restrict__ emb,
                               const void* __restrict__ w,
                               float* __restrict__ acc,
                               unsigned short* __restrict__ src,
                               const int* __restrict__ flag, int n) {
  int r = blockIdx.x * (blockDim.x >> 6) + (threadIdx.x >> 6);
  if (r >= n) return;
  int lane = threadIdx.x & 63;
  int g = lane >> 4, q = lane & 15, d4 = q * 4;
  int start = rowptr[r], deg = cnt[r];
  bool f32 = (*flag != 0);
  float s0 = 0.f, s1 = 0.f, s2 = 0.f, s3 = 0.f;

  if (f32) {
    const float* e = (const float*)emb;
    for (int base = 0; base < deg; base += 64) {
      int take = deg - base; take = take < 64 ? take : 64;
      int c = 0; float vf = 0.f;
      if (lane < take) { c = colA[start + base + lane]; vf = 1.f; }
#pragma unroll 4
      for (int j = 0; j < take; j += 4) {
        int cj = __shfl(c, j + g);
        float dj = __shfl(vf, j + g);
        float4 v = *reinterpret_cast<const float4*>(e + (size_t)cj * kEmb + d4);
        s0 += dj * v.x; s1 += dj * v.y; s2 += dj * v.z; s3 += dj * v.w;
      }
    }
  } else {
    const unsigned short* e = (const unsigned short*)emb;
    for (int base = 0; base < deg; base += 64) {
      int take = deg - base; take = take < 64 ? take : 64;
      int c = 0; float vf = 0.f;
      if (lane < take) { c = colA[start + base + lane]; vf = 1.f; }
#pragma unroll 4
      for (int j = 0; j < take; j += 4) {
        int cj = __shfl(c, j + g);
        float dj = __shfl(vf, j + g);
        ushort4 v = *reinterpret_cast<const ushort4*>(e + (size_t)cj * kEmb + d4);
        s0 += dj * bfu2f(v.x); s1 += dj * bfu2f(v.y);
        s2 += dj * bfu2f(v.z); s3 += dj * bfu2f(v.w);
      }
    }
  }

  s0 += __shfl_xor(s0, 16); s0 += __shfl_xor(s0, 32);
  s1 += __shfl_xor(s1, 16); s1 += __shfl_xor(s1, 32);
  s2 += __shfl_xor(s2, 16); s2 += __shfl_xor(s2, 32);
  s3 += __shfl_xor(s3, 16); s3 += __shfl_xor(s3, 32);

  if (g == 0) {
    int bias = (r < kUsers) ? kN : kN + 1;
    float b0, b1, b2, b3, w0, w1, w2, w3;
    if (f32) {
      float4 bv = *reinterpret_cast<const float4*>((const float*)emb +
                                                   (size_t)bias * kEmb + d4);
      b0 = bv.x; b1 = bv.y; b2 = bv.z; b3 = bv.w;
      float4 wv = *reinterpret_cast<const float4*>((const float*)w + d4);
      w0 = wv.x; w1 = wv.y; w2 = wv.z; w3 = wv.w;
    } else {
      ushort4 bv = *reinterpret_cast<const ushort4*>((const unsigned short*)emb +
                                                     (size_t)bias * kEmb + d4);
      b0 = bfu2f(bv.x); b1 = bfu2f(bv.y); b2 = bfu2f(bv.z); b3 = bfu2f(bv.w);
      ushort4 wv = *reinterpret_cast<const ushort4*>((const unsigned short*)w + d4);
      w0 = bfu2f(wv.x); w1 = bfu2f(wv.y); w2 = bfu2f(wv.z); w3 = bfu2f(wv.w);
    }
    float df = dfinv[r], dr = dinv[r];
    float r0 = df * (s0 + b0) * w0;
    float r1 = df * (s1 + b1) * w1;
    float r2 = df * (s2 + b2) * w2;
    float r3 = df * (s3 + b3) * w3;
    size_t o = (size_t)r * kEmb + d4;
    *reinterpret_cast<float4*>(acc + o) = make_float4(r0, r1, r2, r3);
    ushort4 sb;
    sb.x = f2bfu(dr * r0); sb.y = f2bfu(dr * r1);
    sb.z = f2bfu(dr * r2); sb.w = f2bfu(dr * r3);
    *reinterpret_cast<ushort4*>(src + o) = sb;
  }
}

// ---- propagation SpMM on pre-scaled t: s = sum t[c]; rep = dinv[r]*s ----
// acc += rep ; dst = bf16(dinv[r]*rep)
__global__ void igcn_adj_spmm(const int* __restrict__ rowptr,
                              const int* __restrict__ cnt,
                              const int* __restrict__ colA,
                              const float* __restrict__ dinv,
                              const unsigned short* __restrict__ src,
                              unsigned short* __restrict__ dst,
                              float* __restrict__ acc, int n) {
  int r = blockIdx.x * (blockDim.x >> 6) + (threadIdx.x >> 6);
  if (r >= n) return;
  int lane = threadIdx.x & 63;
  int g = lane >> 4, q = lane & 15, d4 = q * 4;
  int start = rowptr[r], deg = cnt[r];
  float s0 = 0.f, s1 = 0.f, s2 = 0.f, s3 = 0.f;

  for (int base = 0; base < deg; base += 64) {
    int take = deg - base; take = take < 64 ? take : 64;
    int c = 0; float vf = 0.f;
    if (lane < take) { c = colA[start + base + lane]; vf = 1.f; }
#pragma unroll 4
    for (int j = 0; j < take; j += 4) {
      int cj = __shfl(c, j + g);
      float dj = __shfl(vf, j + g);
      ushort4 v = *reinterpret_cast<const ushort4*>(src + (size_t)cj * kEmb + d4);
      s0 += dj * bfu2f(v.x); s1 += dj * bfu2f(v.y);
      s2 += dj * bfu2f(v.z); s3 += dj * bfu2f(v.w);
    }
  }

  s0 += __shfl_xor(s0, 16); s0 += __shfl_xor(s0, 32);
  s1 += __shfl_xor(s1, 16); s1 += __shfl_xor(s1, 32);
  s2 += __shfl_xor(s2, 16); s2 += __shfl_xor(s2, 32);
  s3 += __shfl_xor(s3, 16); s3 += __shfl_xor(s3, 32);

  if (g == 0) {
    float dr = dinv[r];
    float r0 = dr * s0, r1 = dr * s1, r2 = dr * s2, r3 = dr * s3;
    size_t o = (size_t)r * kEmb + d4;
    float4 a = *reinterpret_cast<float4*>(acc + o);
    a.x += r0; a.y += r1; a.z += r2; a.w += r3;
    *reinterpret_cast<float4*>(acc + o) = a;
    ushort4 b;
    b.x = f2bfu(dr * r0); b.y = f2bfu(dr * r1);
    b.z = f2bfu(dr * r2); b.w = f2bfu(dr * r3);
    *reinterpret_cast<ushort4*>(dst + o) = b;
  }
}

// ---- final GEMM: out[b][i] = dot(acc[users[b]]/4, acc[kUsers+i]/4) ----
// 128x128 tile, K=64 resident. Transposed LDS tiles (k-major), float4 reads,
// 8x8 outputs per thread. 64KB LDS -> 2 blocks/CU, FMA-issue-bound.
__global__ __launch_bounds__(256) void igcn_final_gemm(
    const float* __restrict__ acc, const int* __restrict__ users,
    float* __restrict__ outf, unsigned short* __restrict__ outb,
    int batch, const int* __restrict__ flag) {
  __shared__ float Ut[64][128];   // [k][user]
  __shared__ float It[64][128];   // [k][item]
  int itile = blockIdx.x * 128;
  int utile = blockIdx.y * 128;
  int t = threadIdx.x;

  // cooperative load+transpose: thread t covers row (t&127), k-quads (t>>7)+2n
  for (int i = t; i < 128 * 16; i += 256) {
    int row = i & 127;
    int k4  = (i >> 7) * 4;
    float4 uv = make_float4(0.f, 0.f, 0.f, 0.f);
    int ub = utile + row;
    if (ub < batch) {
      int urow = users[ub];
      uv = *reinterpret_cast<const float4*>(acc + (size_t)urow * kEmb + k4);
    }
    Ut[k4 + 0][row] = uv.x * 0.25f; Ut[k4 + 1][row] = uv.y * 0.25f;
    Ut[k4 + 2][row] = uv.z * 0.25f; Ut[k4 + 3][row] = uv.w * 0.25f;

    float4 iv = make_float4(0.f, 0.f, 0.f, 0.f);
    int it = itile + row;
    if (it < kItems)
      iv = *reinterpret_cast<const float4*>(acc + (size_t)(kUsers + it) * kEmb + k4);
    It[k4 + 0][row] = iv.x * 0.25f; It[k4 + 1][row] = iv.y * 0.25f;
    It[k4 + 2][row] = iv.z * 0.25f; It[k4 + 3][row] = iv.w * 0.25f;
  }
  __syncthreads();

  int tx = t & 15, ty = t >> 4;
  int ib  = tx * 8;   // item offset in tile
  int ub0 = ty * 8;   // user offset in tile
  float s[8][8] = {};

#pragma unroll 8
  for (int k = 0; k < 64; ++k) {
    float4 a0 = *reinterpret_cast<const float4*>(&Ut[k][ub0]);
    float4 a1 = *reinterpret_cast<const float4*>(&Ut[k][ub0 + 4]);
    float4 b0 = *reinterpret_cast<const float4*>(&It[k][ib]);
    float4 b1 = *reinterpret_cast<const float4*>(&It[k][ib + 4]);
    float av[8] = {a0.x, a0.y, a0.z, a0.w, a1.x, a1.y, a1.z, a1.w};
    float bv[8] = {b0.x, b0.y, b0.z, b0.w, b1.x, b1.y, b1.z, b1.w};
#pragma unroll
    for (int iu = 0; iu < 8; ++iu)
#pragma unroll
      for (int ii = 0; ii < 8; ++ii)
        s[iu][ii] += av[iu] * bv[ii];
  }

  bool f32 = (*flag != 0);
  int icol0 = itile + ib;
#pragma unroll
  for (int iu = 0; iu < 8; ++iu) {
    int ub = utile + ub0 + iu;
    if (ub >= batch) break;
    size_t o = (size_t)ub * kItems + icol0;
    if (f32) {
      if (icol0 + 7 < kItems) {
        *reinterpret_cast<float4*>(outf + o) =
            make_float4(s[iu][0], s[iu][1], s[iu][2], s[iu][3]);
        *reinterpret_cast<float4*>(outf + o + 4) =
            make_float4(s[iu][4], s[iu][5], s[iu][6], s[iu][7]);
      } else {
        for (int ii = 0; ii < 8; ++ii)
          if (icol0 + ii < kItems) outf[o + ii] = s[iu][ii];
      }
    } else {
      if (icol0 + 7 < kItems) {
        ushort4 p0, p1;
        p0.x = f2bfu(s[iu][0]); p0.y = f2bfu(s[iu][1]);
        p0.z = f2bfu(s[iu][2]); p0.w = f2bfu(s[iu][3]);
        p1.x = f2bfu(s[iu][4]); p1.y = f2bfu(s[iu][5]);
        p1.z = f2bfu(s[iu][6]); p1.w = f2bfu(s[iu][7]);
        *reinterpret_cast<ushort4*>(outb + o) = p0;
        *reinterpret_cast<ushort4*>(outb + o + 4) = p1;
      } else {
        for (int ii = 0; ii < 8; ++ii)
          if (icol0 + ii < kItems) outb[o + ii] = f2bfu(s[iu][ii]);
      }
    }
  }
}

extern "C" void kernel_launch(void* const* d_in, const int* in_sizes, int n_in,
                              void* d_out, int out_size, void* d_ws, size_t ws_size,
                              hipStream_t stream) {
  const int* users   = (const int*)d_in[0];
  const void* emb    = d_in[1];
  const void* w      = d_in[2];
  const int* adj_row = (const int*)d_in[3];
  const int* adj_col = (const int*)d_in[4];

  const int batch = in_sizes[0];
  const int nE    = in_sizes[3];

  // d_ws: [flag | pad | acc fp32 64MB]
  int* flag  = (int*)d_ws;
  float* acc = (float*)((char*)d_ws + 256);

  // d_out scratch layout (bytes)
  char* base = (char*)d_out;
  unsigned short* src = (unsigned short*)(base);                 // 32 MB
  unsigned short* dst = (unsigned short*)(base + (32u << 20));   // 32 MB
  int*   colA   = (int*)  (base + (64u << 20));                  // 16 MB
  int*   cnt    = (int*)  (base + (80u << 20));                  // 1 MB
  int*   rowptr = (int*)  (base + (81u << 20));                  // 1 MB
  int*   cursor = (int*)  (base + (82u << 20));                  // 1 MB
  float* dinv   = (float*)(base + (83u << 20));                  // 1 MB
  float* dfinv  = (float*)(base + (84u << 20));                  // 1 MB
  int*   total  = (int*)  (base + (85u << 20));                  // 4 B

  // 0. dtype detect
  igcn_detect_f32<<<1, 256, 0, stream>>>((const unsigned short*)emb, flag);

  // 1. CSR build
  hipMemsetAsync(cnt, 0, kN * sizeof(int), stream);
  hipMemsetAsync(total, 0, sizeof(int), stream);
  {
    int blocks = (nE + 255) / 256;
    igcn_hist<<<blocks, 256, 0, stream>>>(adj_row, cnt, nE);
  }
  {
    int blocks = (kN + 255) / 256;
    igcn_assign<<<blocks, 256, 0, stream>>>(cnt, rowptr, cursor, dinv, dfinv,
                                            total, kN);
  }
  {
    int blocks = (nE + 255) / 256;
    igcn_scatter<<<blocks, 256, 0, stream>>>(adj_row, adj_col, cursor, colA, nE);
  }

  // 2. feature SpMM (bias edge, dfinv scale, *w, acc init, pre-scaled bf16 t)
  {
    int blocks = (kN + 3) / 4;  // 4 waves per 256-thread block, one row each
    igcn_feat_spmm<<<blocks, 256, 0, stream>>>(rowptr, cnt, colA, dfinv, dinv,
                                               emb, w, acc, src, flag, kN);
  }

  // 3. three propagation layers (fused acc +=), ping-pong src/dst
  for (int l = 0; l < 3; ++l) {
    int blocks = (kN + 3) / 4;
    igcn_adj_spmm<<<blocks, 256, 0, stream>>>(rowptr, cnt, colA, dinv, src, dst,
                                              acc, kN);
    unsigned short* tmp = src; src = dst; dst = tmp;
  }

  // 4. final scoring GEMM (overwrites all of d_out)
  {
    dim3 grid((kItems + 127) / 128, (batch + 127) / 128);
    igcn_final_gemm<<<grid, 256, 0, stream>>>(acc, users,
                                              (float*)d_out,
                                              (unsigned short*)d_out,
                                              batch, flag);
  }
}

// Round 2
// 1474.971 us; speedup vs baseline: 1.4920x; 1.0508x over previous
//
#include <hip/hip_runtime.h>
#include <hip/hip_bf16.h>

// IGCN round 5:
//  - Scatter rebuilt as 2-pass bucket scatter: WRITE_SIZE was 258MB for a 16MB
//    colA (full-line dirty per random 4B store). Bucket cursors make writes
//    sequential per bucket (1024 streams), and a row-ordered CSR (two-level
//    scan) confines pass-2 writes to ~16KB per bucket -> L2-absorbed.
//  - SpMM kernels widened: 8 neighbor groups x 8 lanes, 8 dims/lane via 16B
//    loads -> neighbor chain /2, VMEM+shfl issue count /2.
//  - Propagated rep stored pre-scaled (t = dinv*rep) as before.
//
// Memory: d_ws = [flag | acc fp32 64MB].
//         d_out scratch: src bf16 32MB | dst bf16 32MB | colA 16MB @64MB |
//         rec 16MB @80MB | cnt/rowptr/cursor/dinv/dfinv 1MB each @96..100MB |
//         bkt arrays @101MB. GEMM overwrites d_out last (reads only acc/users).

namespace {
constexpr int kUsers = 100000;
constexpr int kItems = 150000;
constexpr int kN     = 250000;
constexpr int kEmb   = 64;
constexpr int kNB    = 1024;   // buckets of 256 rows
}

__device__ __forceinline__ float bfu2f(unsigned short u) {
  return __uint_as_float((unsigned)u << 16);
}
__device__ __forceinline__ unsigned short f2bfu(float f) {
  unsigned u = __float_as_uint(f);
  u += 0x7FFFu + ((u >> 16) & 1u);   // round-to-nearest-even
  return (unsigned short)(u >> 16);
}
__device__ __forceinline__ float bflo(unsigned u) {
  return __uint_as_float(u << 16);
}
__device__ __forceinline__ float bfhi(unsigned u) {
  return __uint_as_float(u & 0xFFFF0000u);
}
__device__ __forceinline__ unsigned bfpack(float a, float b) {
  return (unsigned)f2bfu(a) | ((unsigned)f2bfu(b) << 16);
}

// ---- dtype detector: flag=1 if fp32 storage, 0 if bf16 ----
__global__ void igcn_detect_f32(const unsigned short* __restrict__ u,
                                int* __restrict__ flag) {
  __shared__ int cnt;
  if (threadIdx.x == 0) cnt = 0;
  __syncthreads();
  int h = 0;
  for (int i = threadIdx.x; i < 4096; i += 256) {
    unsigned e = (u[i] >> 7) & 0xFFu;
    h += (e >= 0x8Eu) ? 1 : 0;
  }
  atomicAdd(&cnt, h);
  __syncthreads();
  if (threadIdx.x == 0) *flag = (cnt > 64) ? 1 : 0;
}

// ---- degree histogram ----
__global__ void igcn_hist(const int* __restrict__ row, int* __restrict__ cnt,
                          int nE) {
  int e = blockIdx.x * blockDim.x + threadIdx.x;
  if (e < nE) atomicAdd(&cnt[row[e]], 1);
}

// ---- assign A: per-bucket (256-row block) local prefix + bucket totals ----
__global__ void igcn_assignA(const int* __restrict__ cnt, int* __restrict__ rowloc,
                             int* __restrict__ bktCnt, float* __restrict__ dinv,
                             float* __restrict__ dfinv, int n) {
  __shared__ int sdata[256];
  int t = threadIdx.x;
  int r = blockIdx.x * 256 + t;
  int c = (r < n) ? cnt[r] : 0;
  sdata[t] = c;
  __syncthreads();
  for (int off = 1; off < 256; off <<= 1) {
    int v = sdata[t];
    int add = (t >= off) ? sdata[t - off] : 0;
    __syncthreads();
    sdata[t] = v + add;
    __syncthreads();
  }
  if (t == 255) bktCnt[blockIdx.x] = sdata[255];
  if (r < n) {
    rowloc[r] = sdata[t] - c;   // exclusive prefix within bucket
    dinv[r]  = rsqrtf((float)(c > 0 ? c : 1));
    dfinv[r] = rsqrtf((float)(c + 1));
  }
}

// ---- bucket scan: exclusive prefix over 1024 bucket counts ----
__global__ void igcn_bktscan(const int* __restrict__ bktCnt,
                             int* __restrict__ bktBase,
                             int* __restrict__ bktCur) {
  __shared__ int a[kNB], b[kNB];
  int t = threadIdx.x;
  int v = bktCnt[t];
  a[t] = v;
  __syncthreads();
  int* cur = a; int* nxt = b;
  for (int off = 1; off < kNB; off <<= 1) {
    int x = cur[t] + ((t >= off) ? cur[t - off] : 0);
    nxt[t] = x;
    __syncthreads();
    int* tmp = cur; cur = nxt; nxt = tmp;
  }
  int incl = cur[t];
  int excl = incl - v;
  bktBase[t] = excl;
  bktCur[t * 16] = excl;           // padded cursor: 64B stride
  if (t == kNB - 1) bktBase[kNB] = incl;   // sentinel = nE
}

// ---- assign B: rowptr = bucket base + local prefix; cursor copy ----
__global__ void igcn_assignB(const int* __restrict__ bktBase,
                             int* __restrict__ rowptr, int* __restrict__ cursor,
                             int n) {
  int r = blockIdx.x * 256 + threadIdx.x;
  if (r >= n) return;
  int v = rowptr[r] + bktBase[r >> 8];
  rowptr[r] = v;
  cursor[r] = v;
}

// ---- scatter pass 1: edges -> bucket-ordered packed records ----
// rec = (row_local<<18) | col  (col < 2^18 = 262144 > 250000)
__global__ void igcn_bucket_scatter(const int* __restrict__ row,
                                    const int* __restrict__ col,
                                    int* __restrict__ bktCur,
                                    unsigned* __restrict__ rec, int nE) {
  int e = blockIdx.x * blockDim.x + threadIdx.x;
  if (e >= nE) return;
  int r = row[e], c = col[e];
  int b = r >> 8;
  int p = atomicAdd(&bktCur[b * 16], 1);
  rec[p] = ((unsigned)(r & 255) << 18) | (unsigned)c;
}

// ---- scatter pass 2: records -> final CSR (writes confined per bucket) ----
__global__ void igcn_csr_scatter(const unsigned* __restrict__ rec,
                                 const int* __restrict__ bktBase,
                                 int* __restrict__ cursor,
                                 int* __restrict__ colA, int nE) {
  __shared__ int LB[kNB + 1];
  for (int i = threadIdx.x; i < kNB + 1; i += 256) LB[i] = bktBase[i];
  __syncthreads();
  int e = blockIdx.x * 256 + threadIdx.x;
  if (e >= nE) return;
  unsigned v = rec[e];
  int b = 0;
#pragma unroll
  for (int s = kNB >> 1; s > 0; s >>= 1) {
    int nb = b + s;
    if (nb < kNB && LB[nb] <= e) b = nb;
  }
  int r = (b << 8) | (int)(v >> 18);
  int c = (int)(v & 0x3FFFFu);
  int p = atomicAdd(&cursor[r], 1);
  colA[p] = c;
}

// ---- feature SpMM: rep = dfinv[r]*(sum emb[c] + emb[bias])*w ----
// acc := rep ; src := bf16(dinv[r]*rep)
// Wave: 8 groups of 8 lanes; group g handles neighbor j+g; lane owns 8 dims.
__global__ void igcn_feat_spmm(const int* __restrict__ rowptr,
                               const int* __restrict__ cnt,
                               const int* __restrict__ colA,
                               const float* __restrict__ dfinv,
                               const float* __restrict__ dinv,
                               const void* __restrict__ emb,
                               const void* __restrict__ w,
                               float* __restrict__ acc,
                               unsigned* __restrict__ src,
                               const int* __restrict__ flag, int n) {
  int r = blockIdx.x * (blockDim.x >> 6) + (threadIdx.x >> 6);
  if (r >= n) return;
  int lane = threadIdx.x & 63;
  int g = lane >> 3, d8 = (lane & 7) * 8;
  int start = rowptr[r], deg = cnt[r];
  bool f32 = (*flag != 0);
  float s0 = 0.f, s1 = 0.f, s2 = 0.f, s3 = 0.f;
  float s4 = 0.f, s5 = 0.f, s6 = 0.f, s7 = 0.f;

  if (f32) {
    const float* e = (const float*)emb;
    for (int base = 0; base < deg; base += 64) {
      int take = deg - base; take = take < 64 ? take : 64;
      int c = 0; float vf = 0.f;
      if (lane < take) { c = colA[start + base + lane]; vf = 1.f; }
#pragma unroll 2
      for (int j = 0; j < take; j += 8) {
        int cj = __shfl(c, j + g);
        float dj = __shfl(vf, j + g);
        const float* rp = e + (size_t)cj * kEmb + d8;
        float4 v0 = *reinterpret_cast<const float4*>(rp);
        float4 v1 = *reinterpret_cast<const float4*>(rp + 4);
        s0 += dj * v0.x; s1 += dj * v0.y; s2 += dj * v0.z; s3 += dj * v0.w;
        s4 += dj * v1.x; s5 += dj * v1.y; s6 += dj * v1.z; s7 += dj * v1.w;
      }
    }
  } else {
    const unsigned* e = (const unsigned*)emb;   // bf16 pairs
    for (int base = 0; base < deg; base += 64) {
      int take = deg - base; take = take < 64 ? take : 64;
      int c = 0; float vf = 0.f;
      if (lane < take) { c = colA[start + base + lane]; vf = 1.f; }
#pragma unroll 2
      for (int j = 0; j < take; j += 8) {
        int cj = __shfl(c, j + g);
        float dj = __shfl(vf, j + g);
        uint4 v = *reinterpret_cast<const uint4*>(
            e + (size_t)cj * (kEmb / 2) + (d8 >> 1));
        s0 += dj * bflo(v.x); s1 += dj * bfhi(v.x);
        s2 += dj * bflo(v.y); s3 += dj * bfhi(v.y);
        s4 += dj * bflo(v.z); s5 += dj * bfhi(v.z);
        s6 += dj * bflo(v.w); s7 += dj * bfhi(v.w);
      }
    }
  }

  s0 += __shfl_xor(s0, 8); s0 += __shfl_xor(s0, 16); s0 += __shfl_xor(s0, 32);
  s1 += __shfl_xor(s1, 8); s1 += __shfl_xor(s1, 16); s1 += __shfl_xor(s1, 32);
  s2 += __shfl_xor(s2, 8); s2 += __shfl_xor(s2, 16); s2 += __shfl_xor(s2, 32);
  s3 += __shfl_xor(s3, 8); s3 += __shfl_xor(s3, 16); s3 += __shfl_xor(s3, 32);
  s4 += __shfl_xor(s4, 8); s4 += __shfl_xor(s4, 16); s4 += __shfl_xor(s4, 32);
  s5 += __shfl_xor(s5, 8); s5 += __shfl_xor(s5, 16); s5 += __shfl_xor(s5, 32);
  s6 += __shfl_xor(s6, 8); s6 += __shfl_xor(s6, 16); s6 += __shfl_xor(s6, 32);
  s7 += __shfl_xor(s7, 8); s7 += __shfl_xor(s7, 16); s7 += __shfl_xor(s7, 32);

  if (g == 0) {
    float b_[8], w_[8];
    int bias = (r < kUsers) ? kN : kN + 1;
    if (f32) {
      const float* ef = (const float*)emb;
      const float* wf = (const float*)w;
      float4 b0 = *reinterpret_cast<const float4*>(ef + (size_t)bias * kEmb + d8);
      float4 b1 = *reinterpret_cast<const float4*>(ef + (size_t)bias * kEmb + d8 + 4);
      float4 w0 = *reinterpret_cast<const float4*>(wf + d8);
      float4 w1 = *reinterpret_cast<const float4*>(wf + d8 + 4);
      b_[0]=b0.x; b_[1]=b0.y; b_[2]=b0.z; b_[3]=b0.w;
      b_[4]=b1.x; b_[5]=b1.y; b_[6]=b1.z; b_[7]=b1.w;
      w_[0]=w0.x; w_[1]=w0.y; w_[2]=w0.z; w_[3]=w0.w;
      w_[4]=w1.x; w_[5]=w1.y; w_[6]=w1.z; w_[7]=w1.w;
    } else {
      const unsigned* eb = (const unsigned*)emb;
      const unsigned* wb = (const unsigned*)w;
      uint4 bv = *reinterpret_cast<const uint4*>(
          eb + (size_t)bias * (kEmb / 2) + (d8 >> 1));
      uint4 wv = *reinterpret_cast<const uint4*>(wb + (d8 >> 1));
      b_[0]=bflo(bv.x); b_[1]=bfhi(bv.x); b_[2]=bflo(bv.y); b_[3]=bfhi(bv.y);
      b_[4]=bflo(bv.z); b_[5]=bfhi(bv.z); b_[6]=bflo(bv.w); b_[7]=bfhi(bv.w);
      w_[0]=bflo(wv.x); w_[1]=bfhi(wv.x); w_[2]=bflo(wv.y); w_[3]=bfhi(wv.y);
      w_[4]=bflo(wv.z); w_[5]=bfhi(wv.z); w_[6]=bflo(wv.w); w_[7]=bfhi(wv.w);
    }
    float df = dfinv[r], dr = dinv[r];
    float sv[8] = {s0, s1, s2, s3, s4, s5, s6, s7};
    float rep[8];
#pragma unroll
    for (int k = 0; k < 8; ++k) rep[k] = df * (sv[k] + b_[k]) * w_[k];
    size_t o = (size_t)r * kEmb + d8;
    *reinterpret_cast<float4*>(acc + o)     = make_float4(rep[0], rep[1], rep[2], rep[3]);
    *reinterpret_cast<float4*>(acc + o + 4) = make_float4(rep[4], rep[5], rep[6], rep[7]);
    uint4 sb;
    sb.x = bfpack(dr * rep[0], dr * rep[1]);
    sb.y = bfpack(dr * rep[2], dr * rep[3]);
    sb.z = bfpack(dr * rep[4], dr * rep[5]);
    sb.w = bfpack(dr * rep[6], dr * rep[7]);
    *reinterpret_cast<uint4*>(src + (size_t)r * (kEmb / 2) + (d8 >> 1)) = sb;
  }
}

// ---- propagation SpMM on pre-scaled t: s = sum t[c]; rep = dinv[r]*s ----
// acc += rep ; dst = bf16(dinv[r]*rep)
__global__ void igcn_adj_spmm(const int* __restrict__ rowptr,
                              const int* __restrict__ cnt,
                              const int* __restrict__ colA,
                              const float* __restrict__ dinv,
                              const unsigned* __restrict__ src,
                              unsigned* __restrict__ dst,
                              float* __restrict__ acc, int n) {
  int r = blockIdx.x * (blockDim.x >> 6) + (threadIdx.x >> 6);
  if (r >= n) return;
  int lane = threadIdx.x & 63;
  int g = lane >> 3, d8 = (lane & 7) * 8;
  int start = rowptr[r], deg = cnt[r];
  float s0 = 0.f, s1 = 0.f, s2 = 0.f, s3 = 0.f;
  float s4 = 0.f, s5 = 0.f, s6 = 0.f, s7 = 0.f;

  for (int base = 0; base < deg; base += 64) {
    int take = deg - base; take = take < 64 ? take : 64;
    int c = 0; float vf = 0.f;
    if (lane < take) { c = colA[start + base + lane]; vf = 1.f; }
#pragma unroll 2
    for (int j = 0; j < take; j += 8) {
      int cj = __shfl(c, j + g);
      float dj = __shfl(vf, j + g);
      uint4 v = *reinterpret_cast<const uint4*>(
          src + (size_t)cj * (kEmb / 2) + (d8 >> 1));
      s0 += dj * bflo(v.x); s1 += dj * bfhi(v.x);
      s2 += dj * bflo(v.y); s3 += dj * bfhi(v.y);
      s4 += dj * bflo(v.z); s5 += dj * bfhi(v.z);
      s6 += dj * bflo(v.w); s7 += dj * bfhi(v.w);
    }
  }

  s0 += __shfl_xor(s0, 8); s0 += __shfl_xor(s0, 16); s0 += __shfl_xor(s0, 32);
  s1 += __shfl_xor(s1, 8); s1 += __shfl_xor(s1, 16); s1 += __shfl_xor(s1, 32);
  s2 += __shfl_xor(s2, 8); s2 += __shfl_xor(s2, 16); s2 += __shfl_xor(s2, 32);
  s3 += __shfl_xor(s3, 8); s3 += __shfl_xor(s3, 16); s3 += __shfl_xor(s3, 32);
  s4 += __shfl_xor(s4, 8); s4 += __shfl_xor(s4, 16); s4 += __shfl_xor(s4, 32);
  s5 += __shfl_xor(s5, 8); s5 += __shfl_xor(s5, 16); s5 += __shfl_xor(s5, 32);
  s6 += __shfl_xor(s6, 8); s6 += __shfl_xor(s6, 16); s6 += __shfl_xor(s6, 32);
  s7 += __shfl_xor(s7, 8); s7 += __shfl_xor(s7, 16); s7 += __shfl_xor(s7, 32);

  if (g == 0) {
    float dr = dinv[r];
    float sv[8] = {s0, s1, s2, s3, s4, s5, s6, s7};
    float rep[8];
#pragma unroll
    for (int k = 0; k < 8; ++k) rep[k] = dr * sv[k];
    size_t o = (size_t)r * kEmb + d8;
    float4 a0 = *reinterpret_cast<float4*>(acc + o);
    float4 a1 = *reinterpret_cast<float4*>(acc + o + 4);
    a0.x += rep[0]; a0.y += rep[1]; a0.z += rep[2]; a0.w += rep[3];
    a1.x += rep[4]; a1.y += rep[5]; a1.z += rep[6]; a1.w += rep[7];
    *reinterpret_cast<float4*>(acc + o)     = a0;
    *reinterpret_cast<float4*>(acc + o + 4) = a1;
    uint4 ob;
    ob.x = bfpack(dr * rep[0], dr * rep[1]);
    ob.y = bfpack(dr * rep[2], dr * rep[3]);
    ob.z = bfpack(dr * rep[4], dr * rep[5]);
    ob.w = bfpack(dr * rep[6], dr * rep[7]);
    *reinterpret_cast<uint4*>(dst + (size_t)r * (kEmb / 2) + (d8 >> 1)) = ob;
  }
}

// ---- final GEMM: out[b][i] = dot(acc[users[b]]/4, acc[kUsers+i]/4) ----
__global__ __launch_bounds__(256) void igcn_final_gemm(
    const float* __restrict__ acc, const int* __restrict__ users,
    float* __restrict__ outf, unsigned short* __restrict__ outb,
    int batch, const int* __restrict__ flag) {
  __shared__ float Ut[64][128];   // [k][user]
  __shared__ float It[64][128];   // [k][item]
  int itile = blockIdx.x * 128;
  int utile = blockIdx.y * 128;
  int t = threadIdx.x;

  for (int i = t; i < 128 * 16; i += 256) {
    int row = i & 127;
    int k4  = (i >> 7) * 4;
    float4 uv = make_float4(0.f, 0.f, 0.f, 0.f);
    int ub = utile + row;
    if (ub < batch) {
      int urow = users[ub];
      uv = *reinterpret_cast<const float4*>(acc + (size_t)urow * kEmb + k4);
    }
    Ut[k4 + 0][row] = uv.x * 0.25f; Ut[k4 + 1][row] = uv.y * 0.25f;
    Ut[k4 + 2][row] = uv.z * 0.25f; Ut[k4 + 3][row] = uv.w * 0.25f;

    float4 iv = make_float4(0.f, 0.f, 0.f, 0.f);
    int it = itile + row;
    if (it < kItems)
      iv = *reinterpret_cast<const float4*>(acc + (size_t)(kUsers + it) * kEmb + k4);
    It[k4 + 0][row] = iv.x * 0.25f; It[k4 + 1][row] = iv.y * 0.25f;
    It[k4 + 2][row] = iv.z * 0.25f; It[k4 + 3][row] = iv.w * 0.25f;
  }
  __syncthreads();

  int tx = t & 15, ty = t >> 4;
  int ib  = tx * 8;
  int ub0 = ty * 8;
  float s[8][8] = {};

#pragma unroll 8
  for (int k = 0; k < 64; ++k) {
    float4 a0 = *reinterpret_cast<const float4*>(&Ut[k][ub0]);
    float4 a1 = *reinterpret_cast<const float4*>(&Ut[k][ub0 + 4]);
    float4 b0 = *reinterpret_cast<const float4*>(&It[k][ib]);
    float4 b1 = *reinterpret_cast<const float4*>(&It[k][ib + 4]);
    float av[8] = {a0.x, a0.y, a0.z, a0.w, a1.x, a1.y, a1.z, a1.w};
    float bv[8] = {b0.x, b0.y, b0.z, b0.w, b1.x, b1.y, b1.z, b1.w};
#pragma unroll
    for (int iu = 0; iu < 8; ++iu)
#pragma unroll
      for (int ii = 0; ii < 8; ++ii)
        s[iu][ii] += av[iu] * bv[ii];
  }

  bool f32 = (*flag != 0);
  int icol0 = itile + ib;
#pragma unroll
  for (int iu = 0; iu < 8; ++iu) {
    int ub = utile + ub0 + iu;
    if (ub >= batch) break;
    size_t o = (size_t)ub * kItems + icol0;
    if (f32) {
      if (icol0 + 7 < kItems) {
        *reinterpret_cast<float4*>(outf + o) =
            make_float4(s[iu][0], s[iu][1], s[iu][2], s[iu][3]);
        *reinterpret_cast<float4*>(outf + o + 4) =
            make_float4(s[iu][4], s[iu][5], s[iu][6], s[iu][7]);
      } else {
        for (int ii = 0; ii < 8; ++ii)
          if (icol0 + ii < kItems) outf[o + ii] = s[iu][ii];
      }
    } else {
      if (icol0 + 7 < kItems) {
        ushort4 p0, p1;
        p0.x = f2bfu(s[iu][0]); p0.y = f2bfu(s[iu][1]);
        p0.z = f2bfu(s[iu][2]); p0.w = f2bfu(s[iu][3]);
        p1.x = f2bfu(s[iu][4]); p1.y = f2bfu(s[iu][5]);
        p1.z = f2bfu(s[iu][6]); p1.w = f2bfu(s[iu][7]);
        *reinterpret_cast<ushort4*>(outb + o) = p0;
        *reinterpret_cast<ushort4*>(outb + o + 4) = p1;
      } else {
        for (int ii = 0; ii < 8; ++ii)
          if (icol0 + ii < kItems) outb[o + ii] = f2bfu(s[iu][ii]);
      }
    }
  }
}

extern "C" void kernel_launch(void* const* d_in, const int* in_sizes, int n_in,
                              void* d_out, int out_size, void* d_ws, size_t ws_size,
                              hipStream_t stream) {
  const int* users   = (const int*)d_in[0];
  const void* emb    = d_in[1];
  const void* w      = d_in[2];
  const int* adj_row = (const int*)d_in[3];
  const int* adj_col = (const int*)d_in[4];

  const int batch = in_sizes[0];
  const int nE    = in_sizes[3];

  // d_ws: [flag | pad | acc fp32 64MB]
  int* flag  = (int*)d_ws;
  float* acc = (float*)((char*)d_ws + 256);

  // d_out scratch layout (bytes)
  char* base = (char*)d_out;
  unsigned* src   = (unsigned*)(base);                       // 32 MB bf16 pairs
  unsigned* dst   = (unsigned*)(base + (32u << 20));         // 32 MB
  int*      colA  = (int*)     (base + (64u << 20));         // 16 MB
  unsigned* rec   = (unsigned*)(base + (80u << 20));         // 16 MB
  int*   cnt      = (int*)  (base + (96u << 20));            // 1 MB
  int*   rowptr   = (int*)  (base + (97u << 20));            // 1 MB
  int*   cursor   = (int*)  (base + (98u << 20));            // 1 MB
  float* dinv     = (float*)(base + (99u << 20));            // 1 MB
  float* dfinv    = (float*)(base + (100u << 20));           // 1 MB
  int*   bktCnt   = (int*)  (base + (101u << 20));           // 4 KB
  int*   bktBase  = (int*)  (base + (101u << 20) + (64u << 10)); // 4+ KB
  int*   bktCur   = (int*)  (base + (101u << 20) + (128u << 10)); // 64 KB padded

  // 0. dtype detect
  igcn_detect_f32<<<1, 256, 0, stream>>>((const unsigned short*)emb, flag);

  // 1. CSR build (row-ordered, two-level scan + 2-pass bucket scatter)
  hipMemsetAsync(cnt, 0, kN * sizeof(int), stream);
  {
    int blocks = (nE + 255) / 256;
    igcn_hist<<<blocks, 256, 0, stream>>>(adj_row, cnt, nE);
  }
  igcn_assignA<<<kNB, 256, 0, stream>>>(cnt, rowptr, bktCnt, dinv, dfinv, kN);
  igcn_bktscan<<<1, kNB, 0, stream>>>(bktCnt, bktBase, bktCur);
  {
    int blocks = (kN + 255) / 256;
    igcn_assignB<<<blocks, 256, 0, stream>>>(bktBase, rowptr, cursor, kN);
  }
  {
    int blocks = (nE + 255) / 256;
    igcn_bucket_scatter<<<blocks, 256, 0, stream>>>(adj_row, adj_col, bktCur,
                                                    rec, nE);
    igcn_csr_scatter<<<blocks, 256, 0, stream>>>(rec, bktBase, cursor, colA, nE);
  }

  // 2. feature SpMM (bias edge, dfinv scale, *w, acc init, pre-scaled bf16 t)
  {
    int blocks = (kN + 3) / 4;  // 4 waves per 256-thread block, one row each
    igcn_feat_spmm<<<blocks, 256, 0, stream>>>(rowptr, cnt, colA, dfinv, dinv,
                                               emb, w, acc, src, flag, kN);
  }

  // 3. three propagation layers (fused acc +=), ping-pong src/dst
  for (int l = 0; l < 3; ++l) {
    int blocks = (kN + 3) / 4;
    igcn_adj_spmm<<<blocks, 256, 0, stream>>>(rowptr, cnt, colA, dinv, src, dst,
                                              acc, kN);
    unsigned* tmp = src; src = dst; dst = tmp;
  }

  // 4. final scoring GEMM (overwrites all of d_out; reads only acc/users)
  {
    dim3 grid((kItems + 127) / 128, (batch + 127) / 128);
    igcn_final_gemm<<<grid, 256, 0, stream>>>(acc, users,
                                              (float*)d_out,
                                              (unsigned short*)d_out,
                                              batch, flag);
  }
}

// Round 3
// 1367.800 us; speedup vs baseline: 1.6089x; 1.0784x over previous
//
#include <hip/hip_runtime.h>
#include <hip/hip_bf16.h>

// IGCN round 6:
//  - Pass-1 scatter sharded by L2 domain: rec slot = (bucket, blockIdx&7), each
//    slot written only by one XCD's blocks -> partial lines merge in that L2
//    instead of 8 incoherent copies (round-5 WRITE was 200MB for 16MB of rec).
//    Fixed slot cap 2048 (mean 512, ~70 sigma) + global overflow fallback.
//    Degree histogram fused into the same pass (one edge read instead of two).
//  - Pass-2 rebuilt as per-bucket LDS counting sort: block stages its bucket's
//    whole CSR segment in LDS (cursors seeded from rowptr), then streams colA
//    out sequentially -> one writer per line, no binary search, no global
//    atomics on cursor.
//  - SpMM (8 groups x 8 lanes, 16B loads, pre-scaled t) and 128x128 GEMM
//    unchanged from round 5.
//
// Memory: d_ws = [flag | acc fp32 64MB].
//         d_out scratch (d_out >= 153MB even in bf16-out mode):
//           src 32MB @0 | dst 32MB @32 | colA 16MB @64 | rec 64MB @80 |
//           cnt @144 | rowptr @145 | dinv @146 | dfinv @147 |
//           bktCnt @148 | bktBase @148+64K | cur2 512KB @148+128K |
//           ovfCnt/ovfR/ovfC @148+640K.. ; GEMM overwrites d_out last.

namespace {
constexpr int kUsers = 100000;
constexpr int kItems = 150000;
constexpr int kN     = 250000;
constexpr int kEmb   = 64;
constexpr int kNB    = 1024;            // scan width (buckets of 256 rows)
constexpr int kNBkt  = (kN + 255) >> 8; // 977 real buckets
constexpr int kCapLog = 11;             // 2048 records per (bucket,xcd) slot
constexpr int kOvf   = 65536;
constexpr int kStage = 12288;           // LDS staging (ints) per bucket
}

__device__ __forceinline__ unsigned short f2bfu(float f) {
  unsigned u = __float_as_uint(f);
  u += 0x7FFFu + ((u >> 16) & 1u);   // round-to-nearest-even
  return (unsigned short)(u >> 16);
}
__device__ __forceinline__ float bflo(unsigned u) {
  return __uint_as_float(u << 16);
}
__device__ __forceinline__ float bfhi(unsigned u) {
  return __uint_as_float(u & 0xFFFF0000u);
}
__device__ __forceinline__ unsigned bfpack(float a, float b) {
  return (unsigned)f2bfu(a) | ((unsigned)f2bfu(b) << 16);
}

// ---- dtype detector: flag=1 if fp32 storage, 0 if bf16 ----
__global__ void igcn_detect_f32(const unsigned short* __restrict__ u,
                                int* __restrict__ flag) {
  __shared__ int cnt;
  if (threadIdx.x == 0) cnt = 0;
  __syncthreads();
  int h = 0;
  for (int i = threadIdx.x; i < 4096; i += 256) {
    unsigned e = (u[i] >> 7) & 0xFFu;
    h += (e >= 0x8Eu) ? 1 : 0;
  }
  atomicAdd(&cnt, h);
  __syncthreads();
  if (threadIdx.x == 0) *flag = (cnt > 64) ? 1 : 0;
}

// ---- init: slot cursors to fixed bases, overflow counter to 0 ----
__global__ void igcn_init_cur2(int* __restrict__ cur2, int* __restrict__ ovfCnt) {
  int s = blockIdx.x * 256 + threadIdx.x;
  if (s < 8192) cur2[s * 16] = s << kCapLog;
  if (s == 0) *ovfCnt = 0;
}

// ---- fused pass 1: degree histogram + XCD-sharded bucket scatter ----
// rec slot (b, blockIdx&7): all writers of a slot share an L2 domain (assuming
// round-robin blockIdx->XCD; wrong mapping costs perf only, never correctness).
__global__ void igcn_hist_scatter(const int* __restrict__ row,
                                  const int* __restrict__ col,
                                  int* __restrict__ cnt,
                                  int* __restrict__ cur2,
                                  unsigned* __restrict__ rec,
                                  int* __restrict__ ovfCnt,
                                  int* __restrict__ ovfR,
                                  int* __restrict__ ovfC, int nE) {
  int e = blockIdx.x * 256 + threadIdx.x;
  if (e >= nE) return;
  int r = row[e], c = col[e];
  atomicAdd(&cnt[r], 1);
  int s = ((r >> 8) << 3) | (blockIdx.x & 7);
  int p = atomicAdd(&cur2[s * 16], 1);
  if (p < ((s + 1) << kCapLog)) {
    rec[p] = ((unsigned)(r & 255) << 18) | (unsigned)c;
  } else {
    int q = atomicAdd(ovfCnt, 1);
    if (q < kOvf) { ovfR[q] = r; ovfC[q] = c; }
  }
}

// ---- assign A: per-bucket local prefix + bucket totals + dinv/dfinv ----
__global__ void igcn_assignA(const int* __restrict__ cnt, int* __restrict__ rowloc,
                             int* __restrict__ bktCnt, float* __restrict__ dinv,
                             float* __restrict__ dfinv, int n) {
  __shared__ int sdata[256];
  int t = threadIdx.x;
  int r = blockIdx.x * 256 + t;
  int c = (r < n) ? cnt[r] : 0;
  sdata[t] = c;
  __syncthreads();
  for (int off = 1; off < 256; off <<= 1) {
    int v = sdata[t];
    int add = (t >= off) ? sdata[t - off] : 0;
    __syncthreads();
    sdata[t] = v + add;
    __syncthreads();
  }
  if (t == 255) bktCnt[blockIdx.x] = sdata[255];
  if (r < n) {
    rowloc[r] = sdata[t] - c;   // exclusive prefix within bucket
    dinv[r]  = rsqrtf((float)(c > 0 ? c : 1));
    dfinv[r] = rsqrtf((float)(c + 1));
  }
}

// ---- bucket scan: exclusive prefix over bucket counts ----
__global__ void igcn_bktscan(const int* __restrict__ bktCnt,
                             int* __restrict__ bktBase) {
  __shared__ int a[kNB], b[kNB];
  int t = threadIdx.x;
  int v = bktCnt[t];
  a[t] = v;
  __syncthreads();
  int* cur = a; int* nxt = b;
  for (int off = 1; off < kNB; off <<= 1) {
    int x = cur[t] + ((t >= off) ? cur[t - off] : 0);
    nxt[t] = x;
    __syncthreads();
    int* tmp = cur; cur = nxt; nxt = tmp;
  }
  int incl = cur[t];
  bktBase[t] = incl - v;
  if (t == kNB - 1) bktBase[kNB] = incl;   // sentinel = nE
}

// ---- assign B: rowptr += bucket base ----
__global__ void igcn_assignB(const int* __restrict__ bktBase,
                             int* __restrict__ rowptr, int n) {
  int r = blockIdx.x * 256 + threadIdx.x;
  if (r < n) rowptr[r] += bktBase[r >> 8];
}

// ---- pass 2: per-bucket LDS counting sort -> sequential colA writes ----
__global__ __launch_bounds__(256) void igcn_csr_build(
    const unsigned* __restrict__ rec, const int* __restrict__ cur2,
    const int* __restrict__ bktBase, const int* __restrict__ rowptr,
    const int* __restrict__ ovfCnt, const int* __restrict__ ovfR,
    const int* __restrict__ ovfC, int* __restrict__ colA, int n) {
  __shared__ int lcur[256];
  __shared__ int lcol[kStage];
  int b = blockIdx.x;
  int t = threadIdx.x;
  int base0 = bktBase[b];
  int total = bktBase[b + 1] - base0;
  int rr = (b << 8) + t;
  lcur[t] = (rr < n) ? (rowptr[rr] - base0) : 0;
  __syncthreads();
  bool stage = (total <= kStage);
#pragma unroll
  for (int x = 0; x < 8; ++x) {
    int s = (b << 3) | x;
    int sbase = s << kCapLog;
    int m = cur2[s * 16] - sbase;
    if (m > (1 << kCapLog)) m = (1 << kCapLog);
    for (int i = t; i < m; i += 256) {
      unsigned v = rec[sbase + i];
      int p = atomicAdd(&lcur[v >> 18], 1);
      int c = (int)(v & 0x3FFFFu);
      if (stage) lcol[p] = c; else colA[base0 + p] = c;
    }
  }
  int novf = *ovfCnt; if (novf > kOvf) novf = kOvf;
  for (int i = t; i < novf; i += 256) {
    int r = ovfR[i];
    if ((r >> 8) == b) {
      int p = atomicAdd(&lcur[r & 255], 1);
      int c = ovfC[i];
      if (stage) lcol[p] = c; else colA[base0 + p] = c;
    }
  }
  __syncthreads();
  if (stage) {
    for (int i = t; i < total; i += 256) colA[base0 + i] = lcol[i];
  }
}

// ---- feature SpMM: rep = dfinv[r]*(sum emb[c] + emb[bias])*w ----
// acc := rep ; src := bf16(dinv[r]*rep)
// Wave: 8 groups of 8 lanes; group g handles neighbor j+g; lane owns 8 dims.
__global__ void igcn_feat_spmm(const int* __restrict__ rowptr,
                               const int* __restrict__ cnt,
                               const int* __restrict__ colA,
                               const float* __restrict__ dfinv,
                               const float* __restrict__ dinv,
                               const void* __restrict__ emb,
                               const void* __restrict__ w,
                               float* __restrict__ acc,
                               unsigned* __restrict__ src,
                               const int* __restrict__ flag, int n) {
  int r = blockIdx.x * (blockDim.x >> 6) + (threadIdx.x >> 6);
  if (r >= n) return;
  int lane = threadIdx.x & 63;
  int g = lane >> 3, d8 = (lane & 7) * 8;
  int start = rowptr[r], deg = cnt[r];
  bool f32 = (*flag != 0);
  float s0 = 0.f, s1 = 0.f, s2 = 0.f, s3 = 0.f;
  float s4 = 0.f, s5 = 0.f, s6 = 0.f, s7 = 0.f;

  if (f32) {
    const float* e = (const float*)emb;
    for (int base = 0; base < deg; base += 64) {
      int take = deg - base; take = take < 64 ? take : 64;
      int c = 0; float vf = 0.f;
      if (lane < take) { c = colA[start + base + lane]; vf = 1.f; }
#pragma unroll 2
      for (int j = 0; j < take; j += 8) {
        int cj = __shfl(c, j + g);
        float dj = __shfl(vf, j + g);
        const float* rp = e + (size_t)cj * kEmb + d8;
        float4 v0 = *reinterpret_cast<const float4*>(rp);
        float4 v1 = *reinterpret_cast<const float4*>(rp + 4);
        s0 += dj * v0.x; s1 += dj * v0.y; s2 += dj * v0.z; s3 += dj * v0.w;
        s4 += dj * v1.x; s5 += dj * v1.y; s6 += dj * v1.z; s7 += dj * v1.w;
      }
    }
  } else {
    const unsigned* e = (const unsigned*)emb;   // bf16 pairs
    for (int base = 0; base < deg; base += 64) {
      int take = deg - base; take = take < 64 ? take : 64;
      int c = 0; float vf = 0.f;
      if (lane < take) { c = colA[start + base + lane]; vf = 1.f; }
#pragma unroll 2
      for (int j = 0; j < take; j += 8) {
        int cj = __shfl(c, j + g);
        float dj = __shfl(vf, j + g);
        uint4 v = *reinterpret_cast<const uint4*>(
            e + (size_t)cj * (kEmb / 2) + (d8 >> 1));
        s0 += dj * bflo(v.x); s1 += dj * bfhi(v.x);
        s2 += dj * bflo(v.y); s3 += dj * bfhi(v.y);
        s4 += dj * bflo(v.z); s5 += dj * bfhi(v.z);
        s6 += dj * bflo(v.w); s7 += dj * bfhi(v.w);
      }
    }
  }

  s0 += __shfl_xor(s0, 8); s0 += __shfl_xor(s0, 16); s0 += __shfl_xor(s0, 32);
  s1 += __shfl_xor(s1, 8); s1 += __shfl_xor(s1, 16); s1 += __shfl_xor(s1, 32);
  s2 += __shfl_xor(s2, 8); s2 += __shfl_xor(s2, 16); s2 += __shfl_xor(s2, 32);
  s3 += __shfl_xor(s3, 8); s3 += __shfl_xor(s3, 16); s3 += __shfl_xor(s3, 32);
  s4 += __shfl_xor(s4, 8); s4 += __shfl_xor(s4, 16); s4 += __shfl_xor(s4, 32);
  s5 += __shfl_xor(s5, 8); s5 += __shfl_xor(s5, 16); s5 += __shfl_xor(s5, 32);
  s6 += __shfl_xor(s6, 8); s6 += __shfl_xor(s6, 16); s6 += __shfl_xor(s6, 32);
  s7 += __shfl_xor(s7, 8); s7 += __shfl_xor(s7, 16); s7 += __shfl_xor(s7, 32);

  if (g == 0) {
    float b_[8], w_[8];
    int bias = (r < kUsers) ? kN : kN + 1;
    if (f32) {
      const float* ef = (const float*)emb;
      const float* wf = (const float*)w;
      float4 b0 = *reinterpret_cast<const float4*>(ef + (size_t)bias * kEmb + d8);
      float4 b1 = *reinterpret_cast<const float4*>(ef + (size_t)bias * kEmb + d8 + 4);
      float4 w0 = *reinterpret_cast<const float4*>(wf + d8);
      float4 w1 = *reinterpret_cast<const float4*>(wf + d8 + 4);
      b_[0]=b0.x; b_[1]=b0.y; b_[2]=b0.z; b_[3]=b0.w;
      b_[4]=b1.x; b_[5]=b1.y; b_[6]=b1.z; b_[7]=b1.w;
      w_[0]=w0.x; w_[1]=w0.y; w_[2]=w0.z; w_[3]=w0.w;
      w_[4]=w1.x; w_[5]=w1.y; w_[6]=w1.z; w_[7]=w1.w;
    } else {
      const unsigned* eb = (const unsigned*)emb;
      const unsigned* wb = (const unsigned*)w;
      uint4 bv = *reinterpret_cast<const uint4*>(
          eb + (size_t)bias * (kEmb / 2) + (d8 >> 1));
      uint4 wv = *reinterpret_cast<const uint4*>(wb + (d8 >> 1));
      b_[0]=bflo(bv.x); b_[1]=bfhi(bv.x); b_[2]=bflo(bv.y); b_[3]=bfhi(bv.y);
      b_[4]=bflo(bv.z); b_[5]=bfhi(bv.z); b_[6]=bflo(bv.w); b_[7]=bfhi(bv.w);
      w_[0]=bflo(wv.x); w_[1]=bfhi(wv.x); w_[2]=bflo(wv.y); w_[3]=bfhi(wv.y);
      w_[4]=bflo(wv.z); w_[5]=bfhi(wv.z); w_[6]=bflo(wv.w); w_[7]=bfhi(wv.w);
    }
    float df = dfinv[r], dr = dinv[r];
    float sv[8] = {s0, s1, s2, s3, s4, s5, s6, s7};
    float rep[8];
#pragma unroll
    for (int k = 0; k < 8; ++k) rep[k] = df * (sv[k] + b_[k]) * w_[k];
    size_t o = (size_t)r * kEmb + d8;
    *reinterpret_cast<float4*>(acc + o)     = make_float4(rep[0], rep[1], rep[2], rep[3]);
    *reinterpret_cast<float4*>(acc + o + 4) = make_float4(rep[4], rep[5], rep[6], rep[7]);
    uint4 sb;
    sb.x = bfpack(dr * rep[0], dr * rep[1]);
    sb.y = bfpack(dr * rep[2], dr * rep[3]);
    sb.z = bfpack(dr * rep[4], dr * rep[5]);
    sb.w = bfpack(dr * rep[6], dr * rep[7]);
    *reinterpret_cast<uint4*>(src + (size_t)r * (kEmb / 2) + (d8 >> 1)) = sb;
  }
}

// ---- propagation SpMM on pre-scaled t: s = sum t[c]; rep = dinv[r]*s ----
// acc += rep ; dst = bf16(dinv[r]*rep)
__global__ void igcn_adj_spmm(const int* __restrict__ rowptr,
                              const int* __restrict__ cnt,
                              const int* __restrict__ colA,
                              const float* __restrict__ dinv,
                              const unsigned* __restrict__ src,
                              unsigned* __restrict__ dst,
                              float* __restrict__ acc, int n) {
  int r = blockIdx.x * (blockDim.x >> 6) + (threadIdx.x >> 6);
  if (r >= n) return;
  int lane = threadIdx.x & 63;
  int g = lane >> 3, d8 = (lane & 7) * 8;
  int start = rowptr[r], deg = cnt[r];
  float s0 = 0.f, s1 = 0.f, s2 = 0.f, s3 = 0.f;
  float s4 = 0.f, s5 = 0.f, s6 = 0.f, s7 = 0.f;

  for (int base = 0; base < deg; base += 64) {
    int take = deg - base; take = take < 64 ? take : 64;
    int c = 0; float vf = 0.f;
    if (lane < take) { c = colA[start + base + lane]; vf = 1.f; }
#pragma unroll 2
    for (int j = 0; j < take; j += 8) {
      int cj = __shfl(c, j + g);
      float dj = __shfl(vf, j + g);
      uint4 v = *reinterpret_cast<const uint4*>(
          src + (size_t)cj * (kEmb / 2) + (d8 >> 1));
      s0 += dj * bflo(v.x); s1 += dj * bfhi(v.x);
      s2 += dj * bflo(v.y); s3 += dj * bfhi(v.y);
      s4 += dj * bflo(v.z); s5 += dj * bfhi(v.z);
      s6 += dj * bflo(v.w); s7 += dj * bfhi(v.w);
    }
  }

  s0 += __shfl_xor(s0, 8); s0 += __shfl_xor(s0, 16); s0 += __shfl_xor(s0, 32);
  s1 += __shfl_xor(s1, 8); s1 += __shfl_xor(s1, 16); s1 += __shfl_xor(s1, 32);
  s2 += __shfl_xor(s2, 8); s2 += __shfl_xor(s2, 16); s2 += __shfl_xor(s2, 32);
  s3 += __shfl_xor(s3, 8); s3 += __shfl_xor(s3, 16); s3 += __shfl_xor(s3, 32);
  s4 += __shfl_xor(s4, 8); s4 += __shfl_xor(s4, 16); s4 += __shfl_xor(s4, 32);
  s5 += __shfl_xor(s5, 8); s5 += __shfl_xor(s5, 16); s5 += __shfl_xor(s5, 32);
  s6 += __shfl_xor(s6, 8); s6 += __shfl_xor(s6, 16); s6 += __shfl_xor(s6, 32);
  s7 += __shfl_xor(s7, 8); s7 += __shfl_xor(s7, 16); s7 += __shfl_xor(s7, 32);

  if (g == 0) {
    float dr = dinv[r];
    float sv[8] = {s0, s1, s2, s3, s4, s5, s6, s7};
    float rep[8];
#pragma unroll
    for (int k = 0; k < 8; ++k) rep[k] = dr * sv[k];
    size_t o = (size_t)r * kEmb + d8;
    float4 a0 = *reinterpret_cast<float4*>(acc + o);
    float4 a1 = *reinterpret_cast<float4*>(acc + o + 4);
    a0.x += rep[0]; a0.y += rep[1]; a0.z += rep[2]; a0.w += rep[3];
    a1.x += rep[4]; a1.y += rep[5]; a1.z += rep[6]; a1.w += rep[7];
    *reinterpret_cast<float4*>(acc + o)     = a0;
    *reinterpret_cast<float4*>(acc + o + 4) = a1;
    uint4 ob;
    ob.x = bfpack(dr * rep[0], dr * rep[1]);
    ob.y = bfpack(dr * rep[2], dr * rep[3]);
    ob.z = bfpack(dr * rep[4], dr * rep[5]);
    ob.w = bfpack(dr * rep[6], dr * rep[7]);
    *reinterpret_cast<uint4*>(dst + (size_t)r * (kEmb / 2) + (d8 >> 1)) = ob;
  }
}

// ---- final GEMM: out[b][i] = dot(acc[users[b]]/4, acc[kUsers+i]/4) ----
__global__ __launch_bounds__(256) void igcn_final_gemm(
    const float* __restrict__ acc, const int* __restrict__ users,
    float* __restrict__ outf, unsigned short* __restrict__ outb,
    int batch, const int* __restrict__ flag) {
  __shared__ float Ut[64][128];   // [k][user]
  __shared__ float It[64][128];   // [k][item]
  int itile = blockIdx.x * 128;
  int utile = blockIdx.y * 128;
  int t = threadIdx.x;

  for (int i = t; i < 128 * 16; i += 256) {
    int row = i & 127;
    int k4  = (i >> 7) * 4;
    float4 uv = make_float4(0.f, 0.f, 0.f, 0.f);
    int ub = utile + row;
    if (ub < batch) {
      int urow = users[ub];
      uv = *reinterpret_cast<const float4*>(acc + (size_t)urow * kEmb + k4);
    }
    Ut[k4 + 0][row] = uv.x * 0.25f; Ut[k4 + 1][row] = uv.y * 0.25f;
    Ut[k4 + 2][row] = uv.z * 0.25f; Ut[k4 + 3][row] = uv.w * 0.25f;

    float4 iv = make_float4(0.f, 0.f, 0.f, 0.f);
    int it = itile + row;
    if (it < kItems)
      iv = *reinterpret_cast<const float4*>(acc + (size_t)(kUsers + it) * kEmb + k4);
    It[k4 + 0][row] = iv.x * 0.25f; It[k4 + 1][row] = iv.y * 0.25f;
    It[k4 + 2][row] = iv.z * 0.25f; It[k4 + 3][row] = iv.w * 0.25f;
  }
  __syncthreads();

  int tx = t & 15, ty = t >> 4;
  int ib  = tx * 8;
  int ub0 = ty * 8;
  float s[8][8] = {};

#pragma unroll 8
  for (int k = 0; k < 64; ++k) {
    float4 a0 = *reinterpret_cast<const float4*>(&Ut[k][ub0]);
    float4 a1 = *reinterpret_cast<const float4*>(&Ut[k][ub0 + 4]);
    float4 b0 = *reinterpret_cast<const float4*>(&It[k][ib]);
    float4 b1 = *reinterpret_cast<const float4*>(&It[k][ib + 4]);
    float av[8] = {a0.x, a0.y, a0.z, a0.w, a1.x, a1.y, a1.z, a1.w};
    float bv[8] = {b0.x, b0.y, b0.z, b0.w, b1.x, b1.y, b1.z, b1.w};
#pragma unroll
    for (int iu = 0; iu < 8; ++iu)
#pragma unroll
      for (int ii = 0; ii < 8; ++ii)
        s[iu][ii] += av[iu] * bv[ii];
  }

  bool f32 = (*flag != 0);
  int icol0 = itile + ib;
#pragma unroll
  for (int iu = 0; iu < 8; ++iu) {
    int ub = utile + ub0 + iu;
    if (ub >= batch) break;
    size_t o = (size_t)ub * kItems + icol0;
    if (f32) {
      if (icol0 + 7 < kItems) {
        *reinterpret_cast<float4*>(outf + o) =
            make_float4(s[iu][0], s[iu][1], s[iu][2], s[iu][3]);
        *reinterpret_cast<float4*>(outf + o + 4) =
            make_float4(s[iu][4], s[iu][5], s[iu][6], s[iu][7]);
      } else {
        for (int ii = 0; ii < 8; ++ii)
          if (icol0 + ii < kItems) outf[o + ii] = s[iu][ii];
      }
    } else {
      if (icol0 + 7 < kItems) {
        ushort4 p0, p1;
        p0.x = f2bfu(s[iu][0]); p0.y = f2bfu(s[iu][1]);
        p0.z = f2bfu(s[iu][2]); p0.w = f2bfu(s[iu][3]);
        p1.x = f2bfu(s[iu][4]); p1.y = f2bfu(s[iu][5]);
        p1.z = f2bfu(s[iu][6]); p1.w = f2bfu(s[iu][7]);
        *reinterpret_cast<ushort4*>(outb + o) = p0;
        *reinterpret_cast<ushort4*>(outb + o + 4) = p1;
      } else {
        for (int ii = 0; ii < 8; ++ii)
          if (icol0 + ii < kItems) outb[o + ii] = f2bfu(s[iu][ii]);
      }
    }
  }
}

extern "C" void kernel_launch(void* const* d_in, const int* in_sizes, int n_in,
                              void* d_out, int out_size, void* d_ws, size_t ws_size,
                              hipStream_t stream) {
  const int* users   = (const int*)d_in[0];
  const void* emb    = d_in[1];
  const void* w      = d_in[2];
  const int* adj_row = (const int*)d_in[3];
  const int* adj_col = (const int*)d_in[4];

  const int batch = in_sizes[0];
  const int nE    = in_sizes[3];

  // d_ws: [flag | pad | acc fp32 64MB]
  int* flag  = (int*)d_ws;
  float* acc = (float*)((char*)d_ws + 256);

  // d_out scratch layout (bytes)
  char* base = (char*)d_out;
  unsigned* src   = (unsigned*)(base);                       // 32 MB bf16 pairs
  unsigned* dst   = (unsigned*)(base + (32u << 20));         // 32 MB
  int*      colA  = (int*)     (base + (64u << 20));         // 16 MB
  unsigned* rec   = (unsigned*)(base + (80u << 20));         // 64 MB (8192 slots x 2048)
  int*   cnt      = (int*)  (base + (144u << 20));           // 1 MB
  int*   rowptr   = (int*)  (base + (145u << 20));           // 1 MB
  float* dinv     = (float*)(base + (146u << 20));           // 1 MB
  float* dfinv    = (float*)(base + (147u << 20));           // 1 MB
  int*   bktCnt   = (int*)  (base + (148u << 20));           // 4 KB
  int*   bktBase  = (int*)  (base + (148u << 20) + (64u << 10));   // 4+ KB
  int*   cur2     = (int*)  (base + (148u << 20) + (128u << 10));  // 512 KB padded
  int*   ovfCnt   = (int*)  (base + (148u << 20) + (640u << 10));  // 4 B
  int*   ovfR     = (int*)  (base + (148u << 20) + (704u << 10));  // 256 KB
  int*   ovfC     = (int*)  (base + (148u << 20) + (960u << 10));  // 256 KB

  // 0. dtype detect
  igcn_detect_f32<<<1, 256, 0, stream>>>((const unsigned short*)emb, flag);

  // 1. CSR build
  hipMemsetAsync(cnt, 0, kN * sizeof(int), stream);
  igcn_init_cur2<<<32, 256, 0, stream>>>(cur2, ovfCnt);
  {
    int blocks = (nE + 255) / 256;
    igcn_hist_scatter<<<blocks, 256, 0, stream>>>(adj_row, adj_col, cnt, cur2,
                                                  rec, ovfCnt, ovfR, ovfC, nE);
  }
  igcn_assignA<<<kNB, 256, 0, stream>>>(cnt, rowptr, bktCnt, dinv, dfinv, kN);
  igcn_bktscan<<<1, kNB, 0, stream>>>(bktCnt, bktBase);
  {
    int blocks = (kN + 255) / 256;
    igcn_assignB<<<blocks, 256, 0, stream>>>(bktBase, rowptr, kN);
  }
  igcn_csr_build<<<kNBkt, 256, 0, stream>>>(rec, cur2, bktBase, rowptr,
                                            ovfCnt, ovfR, ovfC, colA, kN);

  // 2. feature SpMM (bias edge, dfinv scale, *w, acc init, pre-scaled bf16 t)
  {
    int blocks = (kN + 3) / 4;  // 4 waves per 256-thread block, one row each
    igcn_feat_spmm<<<blocks, 256, 0, stream>>>(rowptr, cnt, colA, dfinv, dinv,
                                               emb, w, acc, src, flag, kN);
  }

  // 3. three propagation layers (fused acc +=), ping-pong src/dst
  for (int l = 0; l < 3; ++l) {
    int blocks = (kN + 3) / 4;
    igcn_adj_spmm<<<blocks, 256, 0, stream>>>(rowptr, cnt, colA, dinv, src, dst,
                                              acc, kN);
    unsigned* tmp = src; src = dst; dst = tmp;
  }

  // 4. final scoring GEMM (overwrites all of d_out; reads only acc/users)
  {
    dim3 grid((kItems + 127) / 128, (batch + 127) / 128);
    igcn_final_gemm<<<grid, 256, 0, stream>>>(acc, users,
                                              (float*)d_out,
                                              (unsigned short*)d_out,
                                              batch, flag);
  }
}